// Round 13
// baseline (174.821 us; speedup 1.0000x reference)
//
#include <hip/hip_runtime.h>
#include <hip/hip_bf16.h>

#define NND 50000
#define NED 800000
#define FD 64
#define PADW 64      // fixed CSR row width; P(deg>64)~1e-18 for Poisson(16)
#define MPAD2 50176  // 196*256 rows, gemm-padded
#define NBLK 196     // ceil(50000/256)
#define NEBLK 3125   // NED/256
#define NXCD 8
#define NPX 6250     // NND/NXCD
#define AVGDL 2.833f

typedef __attribute__((ext_vector_type(8))) short short8;
typedef __attribute__((ext_vector_type(4))) short short4v;
typedef __attribute__((ext_vector_type(4))) float floatx4;

// ---- prep: zero deg/gsum/gsumsq/aggb-tail, convert W to MFMA-B-fragment order
__global__ __launch_bounds__(256) void prep(const float* __restrict__ W,
                                            __hip_bfloat16* __restrict__ Wf,
                                            int* __restrict__ deg,
                                            float* __restrict__ gsum,
                                            float* __restrict__ gsumsq,
                                            __hip_bfloat16* __restrict__ aggb) {
    int i = blockIdx.x * 256 + threadIdx.x;
    if (i < NND) deg[i] = 0;
    if (i < 64) { gsum[i] = 0.f; gsumsq[i] = 0.f; }
    // zero rows NND..MPAD2 of aggb: 176 rows * 256 bf16 = 22528 uints
    if (i < (MPAD2 - NND) * 128) ((unsigned int*)(aggb + (size_t)NND * 256))[i] = 0u;
    if (i < 8 * 12 * 64 * 8) {
        int e = i & 7;
        int l = (i >> 3) & 63;
        int st = i >> 9;
        int t = st % 12, s5 = st / 12;
        int k = 32 * s5 + (l >> 4) * 8 + e;
        int col = 16 * t + (l & 15);
        int g = col >> 6, jj = col & 63;
        Wf[i] = __float2bfloat16(W[(g * 256 + k) * FD + jj]);
    }
}

// ---- single-pass padded-CSR fill; XCD-grouped by dst range.
__global__ __launch_bounds__(256) void fill_csr(const int* __restrict__ src,
                                                const int* __restrict__ dst,
                                                int* __restrict__ deg,
                                                int* __restrict__ csr) {
    int g = blockIdx.x & (NXCD - 1);
    int e = (blockIdx.x >> 3) * 256 + threadIdx.x;
    if (e < NED) {
        int d = dst[e];
        if ((unsigned)(d - g * NPX) < (unsigned)NPX) {
            int slot = atomicAdd(&deg[d], 1);
            if (slot < PADW) csr[d * PADW + slot] = src[e];
        }
    }
}

// ---- one wave per node; lane = (feature-quad q, neighbor-slot sub).
// One dwordx4 load fetches 4 whole h-rows per wave-instruction.
__global__ __launch_bounds__(256) void aggregate(
    const float* __restrict__ h, const int* __restrict__ deg,
    const int* __restrict__ csr, __hip_bfloat16* __restrict__ aggb,
    float* __restrict__ c1, float* __restrict__ c2) {
    int wid = blockIdx.x * 4 + (threadIdx.x >> 6);
    int lane = threadIdx.x & 63;
    if (wid >= NND) return;
    int d = deg[wid];
    if (d > PADW) d = PADW;
    int q = lane & 15, sub = lane >> 4;
    floatx4 s  = (floatx4){0.f, 0.f, 0.f, 0.f};
    floatx4 s2 = (floatx4){0.f, 0.f, 0.f, 0.f};
    floatx4 mx = (floatx4){-INFINITY, -INFINITY, -INFINITY, -INFINITY};
    floatx4 mn = (floatx4){INFINITY, INFINITY, INFINITY, INFINITY};
    if (d > 0) {
        const int* row_idx = csr + wid * PADW;
        int myidx = row_idx[lane < d ? lane : d - 1];
        for (int j = 0; j < d; j += 8) {
            int j0 = j + sub, j1 = j + 4 + sub;
            int jc0 = j0 < d ? j0 : d - 1;
            int jc1 = j1 < d ? j1 : d - 1;
            int i0 = __shfl(myidx, jc0);
            int i1 = __shfl(myidx, jc1);
            floatx4 v0 = *(const floatx4*)(&h[(size_t)i0 * FD + 4 * q]);
            floatx4 v1 = *(const floatx4*)(&h[(size_t)i1 * FD + 4 * q]);
            bool ok0 = j0 < d, ok1 = j1 < d;
            #pragma unroll
            for (int k = 0; k < 4; ++k) {
                float a = ok0 ? v0[k] : 0.f;
                float b = ok1 ? v1[k] : 0.f;
                s[k] += a + b;
                s2[k] += a * a + b * b;
                mx[k] = fmaxf(mx[k], fmaxf(ok0 ? v0[k] : -INFINITY, ok1 ? v1[k] : -INFINITY));
                mn[k] = fminf(mn[k], fminf(ok0 ? v0[k] : INFINITY, ok1 ? v1[k] : INFINITY));
            }
        }
    }
    // fold the 4 neighbor-slot groups (lanes differing in bits 4,5)
    #pragma unroll
    for (int m = 16; m <= 32; m <<= 1) {
        #pragma unroll
        for (int k = 0; k < 4; ++k) {
            s[k]  += __shfl_xor(s[k], m);
            s2[k] += __shfl_xor(s2[k], m);
            mx[k] = fmaxf(mx[k], __shfl_xor(mx[k], m));
            mn[k] = fminf(mn[k], __shfl_xor(mn[k], m));
        }
    }
    float cc1 = 0.f, cc2 = 0.f;
    floatx4 statv = (floatx4){0.f, 0.f, 0.f, 0.f};
    if (d > 0) {
        float degf = (float)d;
        float inv = 1.f / degf;
        #pragma unroll
        for (int k = 0; k < 4; ++k) {
            float mean = s[k] * inv;
            float var = fmaxf(s2[k] * inv - mean * mean, 0.f);
            float stdv = sqrtf(var + 1e-5f);
            statv[k] = (sub == 0) ? mean : (sub == 1) ? mx[k] : (sub == 2) ? mn[k] : stdv;
        }
        float logD = logf(degf + 1.f);
        cc1 = logD / AVGDL;
        cc2 = AVGDL / fmaxf(logD, 1e-12f);
    }
    // lane writes stat block `sub`, features 4q..4q+3, as one 8B store
    union { __hip_bfloat16 b[4]; short4v v; } u;
    #pragma unroll
    for (int k = 0; k < 4; ++k) u.b[k] = __float2bfloat16(statv[k]);
    *(short4v*)(aggb + (size_t)wid * 256 + sub * 64 + 4 * q) = u.v;
    if (lane == 0) { c1[wid] = cc1; c2[wid] = cc2; }
}

// ---- GEMM: 196 blocks x 512 threads; Wf fully staged in LDS (96KB);
// each wave computes 2 row-tiles (32 rows), block covers 256 rows.
__global__ __launch_bounds__(512) void gemm_kernel(
    const __hip_bfloat16* __restrict__ aggb, const __hip_bfloat16* __restrict__ Wf,
    const float* __restrict__ c1, const float* __restrict__ c2,
    const float* __restrict__ bias,
    float* __restrict__ x, float* __restrict__ gsum, float* __restrict__ gsumsq) {
    __shared__ short8 Bsm[6144];   // 96 KB
    __shared__ float cs[64], css[64];
    int tid = threadIdx.x;
    const short8* Wf8 = (const short8*)Wf;
    #pragma unroll
    for (int i = 0; i < 12; ++i) Bsm[i * 512 + tid] = Wf8[i * 512 + tid];
    if (tid < 64) { cs[tid] = 0.f; css[tid] = 0.f; }
    __syncthreads();

    int w = tid >> 6, lane = tid & 63;
    int c = lane & 15, hi = lane >> 4;
    int rowBase = blockIdx.x * 256 + w * 32;   // tile p adds p*16
    const short8* A8 = (const short8*)aggb;    // row stride = 32 short8

    floatx4 acc[2][12];
    #pragma unroll
    for (int p = 0; p < 2; ++p)
        #pragma unroll
        for (int t = 0; t < 12; ++t) acc[p][t] = (floatx4){0.f, 0.f, 0.f, 0.f};

    #pragma unroll
    for (int s5 = 0; s5 < 8; ++s5) {
        short8 a0 = A8[(size_t)(rowBase + c) * 32 + 4 * s5 + hi];
        short8 a1 = A8[(size_t)(rowBase + 16 + c) * 32 + 4 * s5 + hi];
        #pragma unroll
        for (int t = 0; t < 12; ++t) {
            short8 b = Bsm[(s5 * 12 + t) * 64 + lane];
            acc[0][t] = __builtin_amdgcn_mfma_f32_16x16x32_bf16(a0, b, acc[0][t], 0, 0, 0);
            acc[1][t] = __builtin_amdgcn_mfma_f32_16x16x32_bf16(a1, b, acc[1][t], 0, 0, 0);
        }
    }

    float bv[4];
    #pragma unroll
    for (int t = 0; t < 4; ++t) bv[t] = bias[16 * t + c];
    float psum[4] = {0.f, 0.f, 0.f, 0.f}, psq[4] = {0.f, 0.f, 0.f, 0.f};
    #pragma unroll
    for (int p = 0; p < 2; ++p) {
        #pragma unroll
        for (int r = 0; r < 4; ++r) {
            int row = rowBase + p * 16 + hi * 4 + r;
            bool valid = row < NND;
            float c1v = valid ? c1[row] : 0.f;
            float c2v = valid ? c2[row] : 0.f;
            #pragma unroll
            for (int t = 0; t < 4; ++t) {
                float val = acc[p][t][r] + c1v * acc[p][t + 4][r] + c2v * acc[p][t + 8][r] + bv[t];
                if (valid) {
                    x[(size_t)row * FD + 16 * t + c] = val;
                    psum[t] += val;
                    psq[t] += val * val;
                }
            }
        }
    }
    #pragma unroll
    for (int t = 0; t < 4; ++t) {
        float rs = psum[t], rq = psq[t];
        rs += __shfl_xor(rs, 16); rs += __shfl_xor(rs, 32);
        rq += __shfl_xor(rq, 16); rq += __shfl_xor(rq, 32);
        if (hi == 0) { atomicAdd(&cs[16 * t + c], rs); atomicAdd(&css[16 * t + c], rq); }
    }
    __syncthreads();
    if (tid < 64) { atomicAdd(&gsum[tid], cs[tid]); atomicAdd(&gsumsq[tid], css[tid]); }
}

// ---- finalize: BN scale/shift recomputed per block (cheap), then elementwise
__global__ __launch_bounds__(256) void finalize(
    const float* __restrict__ x, const float* __restrict__ h,
    const float* __restrict__ gsum, const float* __restrict__ gsumsq,
    const float* __restrict__ gamma, const float* __restrict__ beta,
    float* __restrict__ out) {
    __shared__ float sc[64], sh[64];
    int tid = threadIdx.x;
    if (tid < 64) {
        float mu = gsum[tid] * (1.f / NND);
        float var = gsumsq[tid] * (1.f / NND) - mu * mu;
        float s = gamma[tid] * rsqrtf(var + 1e-5f);
        sc[tid] = s;
        sh[tid] = beta[tid] - mu * s;
    }
    __syncthreads();
    int i = blockIdx.x * 256 + tid;
    if (i >= NND * FD / 4) return;
    int jj = (i & 15) * 4;
    floatx4 xv = ((const floatx4*)x)[i];
    floatx4 hv = ((const floatx4*)h)[i];
    floatx4 o;
    #pragma unroll
    for (int q = 0; q < 4; ++q) {
        float v = sc[jj + q] * xv[q] + sh[jj + q];
        o[q] = hv[q] + fmaxf(v, 0.f);
    }
    ((floatx4*)out)[i] = o;
}

extern "C" void kernel_launch(void* const* d_in, const int* in_sizes, int n_in,
                              void* d_out, int out_size, void* d_ws, size_t ws_size,
                              hipStream_t stream) {
    const float* h     = (const float*)d_in[0];
    const int*   src   = (const int*)d_in[1];
    const int*   dst   = (const int*)d_in[2];
    const float* W     = (const float*)d_in[3];
    const float* bias  = (const float*)d_in[4];
    const float* gamma = (const float*)d_in[5];
    const float* beta  = (const float*)d_in[6];
    float* out = (float*)d_out;

    char* ws = (char*)d_ws;
    size_t off = 0;
    auto alloc = [&](size_t bytes) -> char* {
        char* p = ws + off;
        off = (off + bytes + 255) & ~(size_t)255;
        return p;
    };
    int* deg        = (int*)alloc(NND * 4);
    int* csr        = (int*)alloc((size_t)NND * PADW * 4);
    float* c1       = (float*)alloc(MPAD2 * 4);
    float* c2       = (float*)alloc(MPAD2 * 4);
    __hip_bfloat16* aggb = (__hip_bfloat16*)alloc((size_t)MPAD2 * 256 * 2);
    __hip_bfloat16* Wf   = (__hip_bfloat16*)alloc(8 * 12 * 64 * 8 * 2);
    float* x        = (float*)alloc((size_t)NND * FD * 4);
    float* gsum     = (float*)alloc(64 * 4);
    float* gsumsq   = (float*)alloc(64 * 4);

    prep<<<NBLK, 256, 0, stream>>>(W, Wf, deg, gsum, gsumsq, aggb);
    fill_csr<<<NEBLK * NXCD, 256, 0, stream>>>(src, dst, deg, csr);
    aggregate<<<(NND + 3) / 4, 256, 0, stream>>>(h, deg, csr, aggb, c1, c2);
    gemm_kernel<<<NBLK, 512, 0, stream>>>(aggb, Wf, c1, c2, bias, x, gsum, gsumsq);
    finalize<<<(NND * FD / 4 + 255) / 256, 256, 0, stream>>>(x, h, gsum, gsumsq, gamma, beta, out);
}

// Round 15
// 173.135 us; speedup vs baseline: 1.0097x; 1.0097x over previous
//
#include <hip/hip_runtime.h>
#include <hip/hip_bf16.h>

#define NND 50000
#define NED 800000
#define FD 64
#define PADW 64      // fixed CSR row width; P(deg>64)~1e-18 for Poisson(16)
#define MPAD2 50176  // 196*256 rows, gemm-padded
#define NBLK 196     // ceil(50000/256)
#define NEBLK 3125   // NED/256
#define NXCD 8
#define NPX 6250     // NND/NXCD
#define AVGDL 2.833f

typedef __attribute__((ext_vector_type(8))) short short8;
typedef __attribute__((ext_vector_type(4))) short short4v;
typedef __attribute__((ext_vector_type(4))) float floatx4;

// ---- prep: zero deg/gsum/gsumsq/aggb-tail, convert W to MFMA-B-fragment order
__global__ __launch_bounds__(256) void prep(const float* __restrict__ W,
                                            __hip_bfloat16* __restrict__ Wf,
                                            int* __restrict__ deg,
                                            float* __restrict__ gsum,
                                            float* __restrict__ gsumsq,
                                            __hip_bfloat16* __restrict__ aggb) {
    int i = blockIdx.x * 256 + threadIdx.x;
    if (i < NND) deg[i] = 0;
    if (i < 64) { gsum[i] = 0.f; gsumsq[i] = 0.f; }
    // zero rows NND..MPAD2 of aggb: 176 rows * 256 bf16 = 22528 uints
    if (i < (MPAD2 - NND) * 128) ((unsigned int*)(aggb + (size_t)NND * 256))[i] = 0u;
    if (i < 8 * 12 * 64 * 8) {
        int e = i & 7;
        int l = (i >> 3) & 63;
        int st = i >> 9;
        int t = st % 12, s5 = st / 12;
        int k = 32 * s5 + (l >> 4) * 8 + e;
        int col = 16 * t + (l & 15);
        int g = col >> 6, jj = col & 63;
        Wf[i] = __float2bfloat16(W[(g * 256 + k) * FD + jj]);
    }
}

// ---- single-pass padded-CSR fill; XCD-grouped by dst range.
__global__ __launch_bounds__(256) void fill_csr(const int* __restrict__ src,
                                                const int* __restrict__ dst,
                                                int* __restrict__ deg,
                                                int* __restrict__ csr) {
    int g = blockIdx.x & (NXCD - 1);
    int e = (blockIdx.x >> 3) * 256 + threadIdx.x;
    if (e < NED) {
        int d = dst[e];
        if ((unsigned)(d - g * NPX) < (unsigned)NPX) {
            int slot = atomicAdd(&deg[d], 1);
            if (slot < PADW) csr[d * PADW + slot] = src[e];
        }
    }
}

// ---- one wave per node; lane = (feature-quad q, neighbor-slot sub).
// Unpredicated inner loop: OOB slots clamp-duplicate the last neighbor row
// (harmless for max/min); sum/sumsq overcount corrected after the fold.
__global__ __launch_bounds__(256) void aggregate(
    const float* __restrict__ h, const int* __restrict__ deg,
    const int* __restrict__ csr, __hip_bfloat16* __restrict__ aggb,
    float* __restrict__ c1, float* __restrict__ c2) {
    int wid = blockIdx.x * 4 + (threadIdx.x >> 6);
    int lane = threadIdx.x & 63;
    if (wid >= NND) return;
    int d = deg[wid];
    if (d > PADW) d = PADW;
    int q = lane & 15, sub = lane >> 4;
    const float* hq = h + 4 * q;
    floatx4 s  = (floatx4){0.f, 0.f, 0.f, 0.f};
    floatx4 s2 = (floatx4){0.f, 0.f, 0.f, 0.f};
    floatx4 mx = (floatx4){-INFINITY, -INFINITY, -INFINITY, -INFINITY};
    floatx4 mn = (floatx4){INFINITY, INFINITY, INFINITY, INFINITY};
    float cc1 = 0.f, cc2 = 0.f;
    floatx4 statv = (floatx4){0.f, 0.f, 0.f, 0.f};
    if (d > 0) {
        const int* row_idx = csr + wid * PADW;
        int myidx = row_idx[lane < d ? lane : d - 1];
        for (int j = 0; j < d; j += 8) {
            int jc0 = j + sub;     jc0 = jc0 < d ? jc0 : d - 1;
            int jc1 = j + 4 + sub; jc1 = jc1 < d ? jc1 : d - 1;
            int i0 = __shfl(myidx, jc0);
            int i1 = __shfl(myidx, jc1);
            floatx4 v0 = *(const floatx4*)(&hq[(size_t)i0 * FD]);
            floatx4 v1 = *(const floatx4*)(&hq[(size_t)i1 * FD]);
            #pragma unroll
            for (int k = 0; k < 4; ++k) {
                s[k] += v0[k] + v1[k];
                s2[k] += v0[k] * v0[k];
                s2[k] += v1[k] * v1[k];
                mx[k] = fmaxf(mx[k], fmaxf(v0[k], v1[k]));
                mn[k] = fminf(mn[k], fminf(v0[k], v1[k]));
            }
        }
        // fold the 4 neighbor-slot groups (lanes differing in bits 4,5)
        #pragma unroll
        for (int m = 16; m <= 32; m <<= 1) {
            #pragma unroll
            for (int k = 0; k < 4; ++k) {
                s[k]  += __shfl_xor(s[k], m);
                s2[k] += __shfl_xor(s2[k], m);
                mx[k] = fmaxf(mx[k], __shfl_xor(mx[k], m));
                mn[k] = fminf(mn[k], __shfl_xor(mn[k], m));
            }
        }
        // subtract the clamp-duplicate overcount: npad copies of the last row
        int npad = (8 - (d & 7)) & 7;
        if (npad > 0) {   // wave-uniform branch
            int il = __shfl(myidx, d - 1);
            floatx4 vl = *(const floatx4*)(&hq[(size_t)il * FD]);
            float np = (float)npad;
            #pragma unroll
            for (int k = 0; k < 4; ++k) {
                s[k]  -= np * vl[k];
                s2[k] -= np * vl[k] * vl[k];
            }
        }
        float degf = (float)d;
        float inv = 1.f / degf;
        #pragma unroll
        for (int k = 0; k < 4; ++k) {
            float mean = s[k] * inv;
            float var = fmaxf(s2[k] * inv - mean * mean, 0.f);
            float stdv = sqrtf(var + 1e-5f);
            statv[k] = (sub == 0) ? mean : (sub == 1) ? mx[k] : (sub == 2) ? mn[k] : stdv;
        }
        float logD = logf(degf + 1.f);
        cc1 = logD / AVGDL;
        cc2 = AVGDL / fmaxf(logD, 1e-12f);
    }
    // lane writes stat block `sub`, features 4q..4q+3, as one 8B store
    union { __hip_bfloat16 b[4]; short4v v; } u;
    #pragma unroll
    for (int k = 0; k < 4; ++k) u.b[k] = __float2bfloat16(statv[k]);
    *(short4v*)(aggb + (size_t)wid * 256 + sub * 64 + 4 * q) = u.v;
    if (lane == 0) { c1[wid] = cc1; c2[wid] = cc2; }
}

// ---- GEMM: 196 blocks x 512 threads; Wf fully staged in LDS (96KB);
// each wave computes 2 row-tiles (32 rows), block covers 256 rows.
__global__ __launch_bounds__(512) void gemm_kernel(
    const __hip_bfloat16* __restrict__ aggb, const __hip_bfloat16* __restrict__ Wf,
    const float* __restrict__ c1, const float* __restrict__ c2,
    const float* __restrict__ bias,
    float* __restrict__ x, float* __restrict__ gsum, float* __restrict__ gsumsq) {
    __shared__ short8 Bsm[6144];   // 96 KB
    __shared__ float cs[64], css[64];
    int tid = threadIdx.x;
    const short8* Wf8 = (const short8*)Wf;
    #pragma unroll
    for (int i = 0; i < 12; ++i) Bsm[i * 512 + tid] = Wf8[i * 512 + tid];
    if (tid < 64) { cs[tid] = 0.f; css[tid] = 0.f; }
    __syncthreads();

    int w = tid >> 6, lane = tid & 63;
    int c = lane & 15, hi = lane >> 4;
    int rowBase = blockIdx.x * 256 + w * 32;   // tile p adds p*16
    const short8* A8 = (const short8*)aggb;    // row stride = 32 short8

    floatx4 acc[2][12];
    #pragma unroll
    for (int p = 0; p < 2; ++p)
        #pragma unroll
        for (int t = 0; t < 12; ++t) acc[p][t] = (floatx4){0.f, 0.f, 0.f, 0.f};

    #pragma unroll
    for (int s5 = 0; s5 < 8; ++s5) {
        short8 a0 = A8[(size_t)(rowBase + c) * 32 + 4 * s5 + hi];
        short8 a1 = A8[(size_t)(rowBase + 16 + c) * 32 + 4 * s5 + hi];
        #pragma unroll
        for (int t = 0; t < 12; ++t) {
            short8 b = Bsm[(s5 * 12 + t) * 64 + lane];
            acc[0][t] = __builtin_amdgcn_mfma_f32_16x16x32_bf16(a0, b, acc[0][t], 0, 0, 0);
            acc[1][t] = __builtin_amdgcn_mfma_f32_16x16x32_bf16(a1, b, acc[1][t], 0, 0, 0);
        }
    }

    float bv[4];
    #pragma unroll
    for (int t = 0; t < 4; ++t) bv[t] = bias[16 * t + c];
    float psum[4] = {0.f, 0.f, 0.f, 0.f}, psq[4] = {0.f, 0.f, 0.f, 0.f};
    #pragma unroll
    for (int p = 0; p < 2; ++p) {
        #pragma unroll
        for (int r = 0; r < 4; ++r) {
            int row = rowBase + p * 16 + hi * 4 + r;
            bool valid = row < NND;
            float c1v = valid ? c1[row] : 0.f;
            float c2v = valid ? c2[row] : 0.f;
            #pragma unroll
            for (int t = 0; t < 4; ++t) {
                float val = acc[p][t][r] + c1v * acc[p][t + 4][r] + c2v * acc[p][t + 8][r] + bv[t];
                if (valid) {
                    x[(size_t)row * FD + 16 * t + c] = val;
                    psum[t] += val;
                    psq[t] += val * val;
                }
            }
        }
    }
    #pragma unroll
    for (int t = 0; t < 4; ++t) {
        float rs = psum[t], rq = psq[t];
        rs += __shfl_xor(rs, 16); rs += __shfl_xor(rs, 32);
        rq += __shfl_xor(rq, 16); rq += __shfl_xor(rq, 32);
        if (hi == 0) { atomicAdd(&cs[16 * t + c], rs); atomicAdd(&css[16 * t + c], rq); }
    }
    __syncthreads();
    if (tid < 64) { atomicAdd(&gsum[tid], cs[tid]); atomicAdd(&gsumsq[tid], css[tid]); }
}

// ---- finalize: BN scale/shift recomputed per block (cheap), then elementwise
__global__ __launch_bounds__(256) void finalize(
    const float* __restrict__ x, const float* __restrict__ h,
    const float* __restrict__ gsum, const float* __restrict__ gsumsq,
    const float* __restrict__ gamma, const float* __restrict__ beta,
    float* __restrict__ out) {
    __shared__ float sc[64], sh[64];
    int tid = threadIdx.x;
    if (tid < 64) {
        float mu = gsum[tid] * (1.f / NND);
        float var = gsumsq[tid] * (1.f / NND) - mu * mu;
        float s = gamma[tid] * rsqrtf(var + 1e-5f);
        sc[tid] = s;
        sh[tid] = beta[tid] - mu * s;
    }
    __syncthreads();
    int i = blockIdx.x * 256 + tid;
    if (i >= NND * FD / 4) return;
    int jj = (i & 15) * 4;
    floatx4 xv = ((const floatx4*)x)[i];
    floatx4 hv = ((const floatx4*)h)[i];
    floatx4 o;
    #pragma unroll
    for (int q = 0; q < 4; ++q) {
        float v = sc[jj + q] * xv[q] + sh[jj + q];
        o[q] = hv[q] + fmaxf(v, 0.f);
    }
    ((floatx4*)out)[i] = o;
}

extern "C" void kernel_launch(void* const* d_in, const int* in_sizes, int n_in,
                              void* d_out, int out_size, void* d_ws, size_t ws_size,
                              hipStream_t stream) {
    const float* h     = (const float*)d_in[0];
    const int*   src   = (const int*)d_in[1];
    const int*   dst   = (const int*)d_in[2];
    const float* W     = (const float*)d_in[3];
    const float* bias  = (const float*)d_in[4];
    const float* gamma = (const float*)d_in[5];
    const float* beta  = (const float*)d_in[6];
    float* out = (float*)d_out;

    char* ws = (char*)d_ws;
    size_t off = 0;
    auto alloc = [&](size_t bytes) -> char* {
        char* p = ws + off;
        off = (off + bytes + 255) & ~(size_t)255;
        return p;
    };
    int* deg        = (int*)alloc(NND * 4);
    int* csr        = (int*)alloc((size_t)NND * PADW * 4);
    float* c1       = (float*)alloc(MPAD2 * 4);
    float* c2       = (float*)alloc(MPAD2 * 4);
    __hip_bfloat16* aggb = (__hip_bfloat16*)alloc((size_t)MPAD2 * 256 * 2);
    __hip_bfloat16* Wf   = (__hip_bfloat16*)alloc(8 * 12 * 64 * 8 * 2);
    float* x        = (float*)alloc((size_t)NND * FD * 4);
    float* gsum     = (float*)alloc(64 * 4);
    float* gsumsq   = (float*)alloc(64 * 4);

    prep<<<NBLK, 256, 0, stream>>>(W, Wf, deg, gsum, gsumsq, aggb);
    fill_csr<<<NEBLK * NXCD, 256, 0, stream>>>(src, dst, deg, csr);
    aggregate<<<(NND + 3) / 4, 256, 0, stream>>>(h, deg, csr, aggb, c1, c2);
    gemm_kernel<<<NBLK, 512, 0, stream>>>(aggb, Wf, c1, c2, bias, x, gsum, gsumsq);
    finalize<<<(NND * FD / 4 + 255) / 256, 256, 0, stream>>>(x, h, gsum, gsumsq, gamma, beta, out);
}